// Round 7
// baseline (124.862 us; speedup 1.0000x reference)
//
#include <hip/hip_runtime.h>

#define SEQ 2048
#define BSZ 2
#define NHEAD 16
#define NBH (BSZ * NHEAD)   // 32
#define HDIM 64
#define QBLK 64
#define KVBLK 64
#define NKV (SEQ / KVBLK)   // 32
#define NQT (SEQ / QBLK)    // 32
#define NSEG 4
#define SEGTILES 8          // KV tiles per segment
#define KSTR 88             // K tile LDS stride (bf16 elems)
#define VSTR 72             // Vt/Zt LDS stride
#define ROWSTRIDE (BSZ * NHEAD * HDIM)

typedef __bf16 bf16x8 __attribute__((ext_vector_type(8)));
typedef __bf16 bf16x4 __attribute__((ext_vector_type(4)));
typedef __bf16 bf16x2 __attribute__((ext_vector_type(2)));
typedef float f32x4 __attribute__((ext_vector_type(4)));
typedef unsigned int uint;
typedef uint uint4v __attribute__((ext_vector_type(4)));

__device__ __forceinline__ int vswz(int row, int col) {
  return row * VSTR + (col ^ (((row >> 2) & 7) << 3));
}

// Partial-attention kernel: one (q-tile, bh, kv-segment) per block.
// Writes additive partials (softmax reference fixed at m'=0).
__global__ __launch_bounds__(256)
void ntk_attn_part(const float* __restrict__ Qg, const float* __restrict__ Kg,
                   const float* __restrict__ Vg, const float* __restrict__ PKg,
                   const float* __restrict__ PKVg, float* __restrict__ num,
                   float* __restrict__ den, int nseg) {
  const int bx = blockIdx.x;
  const int seg = blockIdx.z;
  const int k0 = seg * SEGTILES;
  if (k0 > bx) return;                       // no causal work in this segment
  const int k1 = min(bx, k0 + SEGTILES - 1); // inclusive

  __shared__ __bf16 Ks[KVBLK * KSTR];
  __shared__ __bf16 Vts[HDIM * VSTR];
  __shared__ __bf16 Zts[HDIM * VSTR];
  __shared__ float kks[HDIM];

  const int tid = threadIdx.x;
  const int w = tid >> 6, l = tid & 63, lr = l & 15, lg = l >> 4;
  const int bh = blockIdx.y, h = bh & (NHEAD - 1);
  const int q0 = bx * QBLK;
  const int headoff = bh * HDIM;
  const bool seg0 = (seg == 0);
  const int ss = (nseg == NSEG) ? seg : 0;   // slab index (atomic path -> 0)

  // ---- Q fragments (pre-scaled by 1/sqrt(d)) + phi(Q) ----
  bf16x8 aq[2], pq[2];
  {
    const float* qp = Qg + (size_t)(q0 + w * 16 + lr) * ROWSTRIDE + headoff + lg * 8;
#pragma unroll
    for (int c = 0; c < 2; ++c) {
      const float4 x0 = *(const float4*)(qp + 32 * c);
      const float4 x1 = *(const float4*)(qp + 32 * c + 4);
      const float f[8] = {x0.x, x0.y, x0.z, x0.w, x1.x, x1.y, x1.z, x1.w};
#pragma unroll
      for (int i = 0; i < 8; ++i) {
        aq[c][i] = (__bf16)(f[i] * 0.125f);
        const float xs = f[i] * 0.3535533905932738f;
        pq[c][i] = (__bf16)(xs > 0.f ? xs + 1.f : __expf(xs));
      }
    }
  }

  // ---- stage Zt and |kk| (segment 0 only — it owns the phi-correction) ----
  if (seg0) {
#pragma unroll
    for (int it = 0; it < 4; ++it) {
      const int din = (tid >> 4) + 16 * it;
      const int c4 = (tid & 15) * 4;
      const float4 z = *(const float4*)(PKVg + (size_t)h * HDIM * HDIM +
                                        (size_t)din * HDIM + c4);
      Zts[vswz(c4 + 0, din)] = (__bf16)z.x;
      Zts[vswz(c4 + 1, din)] = (__bf16)z.y;
      Zts[vswz(c4 + 2, din)] = (__bf16)z.z;
      Zts[vswz(c4 + 3, din)] = (__bf16)z.w;
    }
    if (tid < HDIM) kks[tid] = fabsf(PKg[h * HDIM + tid]);
  }

  const f32x4 z4 = {0.f, 0.f, 0.f, 0.f};
  f32x4 oacc[4] = {z4, z4, z4, z4};
  float lsum = 0.f;                     // per-lane, q = lr
  const int qa = q0 + w * 16 + lr;

  // ---- register-staged prefetch ----
  const int stg_r = tid >> 4;
  const int stg_c4 = (tid & 15) * 4;
  float4 kreg[4], vreg[4];
  auto issue_k = [&](int kb) {
#pragma unroll
    for (int it = 0; it < 4; ++it)
      kreg[it] = *(const float4*)(Kg + (size_t)(kb * KVBLK + stg_r + 16 * it) * ROWSTRIDE +
                                  headoff + stg_c4);
  };
  auto issue_v = [&](int kb) {
#pragma unroll
    for (int it = 0; it < 4; ++it)
      vreg[it] = *(const float4*)(Vg + (size_t)(kb * KVBLK + stg_r + 16 * it) * ROWSTRIDE +
                                  headoff + stg_c4);
  };
  auto write_k = [&]() {
#pragma unroll
    for (int it = 0; it < 4; ++it) {
      bf16x4 p = {(__bf16)kreg[it].x, (__bf16)kreg[it].y,
                  (__bf16)kreg[it].z, (__bf16)kreg[it].w};
      *(bf16x4*)&Ks[(stg_r + 16 * it) * KSTR + stg_c4] = p;
    }
  };
  auto write_v = [&]() {
#pragma unroll
    for (int it = 0; it < 4; ++it) {
      const int r = stg_r + 16 * it;
      Vts[vswz(stg_c4 + 0, r)] = (__bf16)vreg[it].x;
      Vts[vswz(stg_c4 + 1, r)] = (__bf16)vreg[it].y;
      Vts[vswz(stg_c4 + 2, r)] = (__bf16)vreg[it].z;
      Vts[vswz(stg_c4 + 3, r)] = (__bf16)vreg[it].w;
    }
  };

  // ---- prologue: tile k0 resident, k0+1 in flight ----
  issue_k(k0); issue_v(k0);
  write_k(); write_v();
  if (k0 + 1 <= k1) { issue_k(k0 + 1); issue_v(k0 + 1); }
  __syncthreads();

  const int src1 = lr + 32 * (lg & 1);
  const int src2 = src1 + 16;
  const bool useO = (lg >= 2);

  // ==== segment loop: swapped QK^T, P in registers ====
  for (int kb = k0; kb <= k1; ++kb) {
    const int kv0 = kb * KVBLK;

    f32x4 s4[4];
    __builtin_amdgcn_s_setprio(1);
#pragma unroll
    for (int nj = 0; nj < 4; ++nj) {
      f32x4 acc = z4;
#pragma unroll
      for (int c = 0; c < 2; ++c) {
        const bf16x8 bk = *(const bf16x8*)&Ks[(nj * 16 + lr) * KSTR + 32 * c + lg * 8];
        acc = __builtin_amdgcn_mfma_f32_16x16x32_bf16(bk, aq[c], acc, 0, 0, 0);
      }
      s4[nj] = acc;
    }
    __builtin_amdgcn_s_setprio(0);

    uint dw[4][2];
    if (kb == bx) {
#pragma unroll
      for (int nj = 0; nj < 4; ++nj) {
        float p[4];
#pragma unroll
        for (int r = 0; r < 4; ++r) {
          const int kabs = kv0 + 16 * nj + 4 * lg + r;
          p[r] = (kabs <= qa) ? __expf(s4[nj][r]) : 0.f;
        }
        lsum += (p[0] + p[1]) + (p[2] + p[3]);
        bf16x2 t0 = {(__bf16)p[0], (__bf16)p[1]};
        bf16x2 t1 = {(__bf16)p[2], (__bf16)p[3]};
        dw[nj][0] = __builtin_bit_cast(uint, t0);
        dw[nj][1] = __builtin_bit_cast(uint, t1);
      }
    } else {
#pragma unroll
      for (int nj = 0; nj < 4; ++nj) {
        float p[4];
#pragma unroll
        for (int r = 0; r < 4; ++r) p[r] = __expf(s4[nj][r]);
        lsum += (p[0] + p[1]) + (p[2] + p[3]);
        bf16x2 t0 = {(__bf16)p[0], (__bf16)p[1]};
        bf16x2 t1 = {(__bf16)p[2], (__bf16)p[3]};
        dw[nj][0] = __builtin_bit_cast(uint, t0);
        dw[nj][1] = __builtin_bit_cast(uint, t1);
      }
    }

#pragma unroll
    for (int c = 0; c < 2; ++c) {
      const uint a0 = __shfl((int)dw[2 * c][0], src1);
      const uint b0 = __shfl((int)dw[2 * c + 1][0], src1);
      const uint a1 = __shfl((int)dw[2 * c][1], src1);
      const uint b1 = __shfl((int)dw[2 * c + 1][1], src1);
      const uint a2 = __shfl((int)dw[2 * c][0], src2);
      const uint b2 = __shfl((int)dw[2 * c + 1][0], src2);
      const uint a3 = __shfl((int)dw[2 * c][1], src2);
      const uint b3 = __shfl((int)dw[2 * c + 1][1], src2);
      uint4v du = {useO ? b0 : a0, useO ? b1 : a1, useO ? b2 : a2, useO ? b3 : a3};
      const bf16x8 pa = __builtin_bit_cast(bf16x8, du);
      __builtin_amdgcn_s_setprio(1);
#pragma unroll
      for (int dj = 0; dj < 4; ++dj) {
        const bf16x8 bv = *(const bf16x8*)&Vts[vswz(dj * 16 + lr, 32 * c + lg * 8)];
        oacc[dj] = __builtin_amdgcn_mfma_f32_16x16x32_bf16(pa, bv, oacc[dj], 0, 0, 0);
      }
      __builtin_amdgcn_s_setprio(0);
    }

    if (kb < k1) {
      __syncthreads();
      write_k(); write_v();
      if (kb + 2 <= k1) { issue_k(kb + 2); issue_v(kb + 2); }
      __syncthreads();
    }
  }

  // ---- denominator partial: rowsum(q=lr) (+ phi_q.kk in seg 0) ----
  float s = lsum;
  s += __shfl_xor(s, 16);
  s += __shfl_xor(s, 32);
  if (seg0) {
    float pkk = 0.f;
#pragma unroll
    for (int c = 0; c < 2; ++c)
#pragma unroll
      for (int i = 0; i < 8; ++i)
        pkk += (float)pq[c][i] * kks[32 * c + lg * 8 + i];
    pkk += __shfl_xor(pkk, 16);
    pkk += __shfl_xor(pkk, 32);
    s += pkk;
  }
  {
    float* dp = den + (size_t)(ss * NBH + bh) * SEQ + q0 + w * 16 + lr;
    if (l < 16) {
      if (nseg == NSEG) *dp = s; else atomicAdd(dp, s);
    }
  }

  // ---- numerator partial: oacc (+ phi_q@Z in seg 0) ----
  f32x4 zacc[4] = {z4, z4, z4, z4};
  if (seg0) {
    __builtin_amdgcn_s_setprio(1);
#pragma unroll
    for (int c = 0; c < 2; ++c) {
#pragma unroll
      for (int dj = 0; dj < 4; ++dj) {
        const bf16x8 bz = *(const bf16x8*)&Zts[vswz(dj * 16 + lr, 32 * c + lg * 8)];
        zacc[dj] = __builtin_amdgcn_mfma_f32_16x16x32_bf16(pq[c], bz, zacc[dj], 0, 0, 0);
      }
    }
    __builtin_amdgcn_s_setprio(0);
  }
#pragma unroll
  for (int r = 0; r < 4; ++r) {
    const int q = q0 + w * 16 + lg * 4 + r;
    float* np = num + ((size_t)(ss * NBH + bh) * SEQ + q) * HDIM;
#pragma unroll
    for (int dj = 0; dj < 4; ++dj) {
      const float v = oacc[dj][r] + zacc[dj][r];
      if (nseg == NSEG) np[dj * 16 + lr] = v;
      else atomicAdd(&np[dj * 16 + lr], v);
    }
  }
}

// Combine: sum valid segment partials, normalize, write output [q][b][h*d].
__global__ __launch_bounds__(256)
void ntk_combine(const float* __restrict__ num, const float* __restrict__ den,
                 float* __restrict__ out, int nseg) {
  const int gid = blockIdx.x * 4 + (threadIdx.x >> 6);  // row id: bh*SEQ+q
  const int lane = threadIdx.x & 63;
  const int bh = gid >> 11;
  const int q = gid & (SEQ - 1);
  const int bx = q >> 6;
  const int nv = (nseg == NSEG) ? min(NSEG, (bx >> 3) + 1) : 1;
  float ns = 0.f, ds = 0.f;
  for (int s = 0; s < nv; ++s) {
    ns += num[((size_t)(s * NBH + bh) * SEQ + q) * HDIM + lane];
    ds += den[(size_t)(s * NBH + bh) * SEQ + q];
  }
  const int b = bh >> 4, h = bh & (NHEAD - 1);
  out[(size_t)q * ROWSTRIDE + b * (NHEAD * HDIM) + h * HDIM + lane] = ns / ds;
}

extern "C" void kernel_launch(void* const* d_in, const int* in_sizes, int n_in,
                              void* d_out, int out_size, void* d_ws, size_t ws_size,
                              hipStream_t stream) {
  const float* Qg  = (const float*)d_in[0];
  const float* Kg  = (const float*)d_in[1];
  const float* Vg  = (const float*)d_in[2];
  const float* PKg  = (const float*)d_in[4];
  const float* PKVg = (const float*)d_in[5];
  float* Og = (float*)d_out;

  const size_t numfl = (size_t)NBH * SEQ * HDIM;   // floats per num slab
  const size_t denfl = (size_t)NBH * SEQ;          // floats per den slab
  const size_t need4 = (NSEG * numfl + NSEG * denfl) * sizeof(float);
  const int nseg = (ws_size >= need4) ? NSEG : 1;

  float* num = (float*)d_ws;
  float* den = num + (size_t)nseg * numfl;
  if (nseg == 1)
    hipMemsetAsync(d_ws, 0, (numfl + denfl) * sizeof(float), stream);

  dim3 g1(NQT, NBH, NSEG);
  ntk_attn_part<<<g1, dim3(256), 0, stream>>>(Qg, Kg, Vg, PKg, PKVg, num, den, nseg);
  const int rows = NBH * SEQ;
  ntk_combine<<<rows / 4, dim3(256), 0, stream>>>(num, den, Og, nseg);
}

// Round 8
// 90.018 us; speedup vs baseline: 1.3871x; 1.3871x over previous
//
#include <hip/hip_runtime.h>

#define SEQ 2048
#define BSZ 2
#define NHEAD 16
#define HDIM 64
#define QBLK 128
#define KVBLK 64
#define NQT (SEQ / QBLK)    // 16
#define KSTR 88             // K tile LDS stride (bf16 elems)
#define VSTR 72             // Vt/Zt LDS stride
#define PSTR 72             // P tile LDS stride
#define ROWSTRIDE (BSZ * NHEAD * HDIM)

typedef __bf16 bf16x8 __attribute__((ext_vector_type(8)));
typedef __bf16 bf16x4 __attribute__((ext_vector_type(4)));
typedef float f32x4 __attribute__((ext_vector_type(4)));

// XOR swizzle on the column index for transposed tiles (Vt, Zt).
__device__ __forceinline__ int vswz(int row, int col) {
  return row * VSTR + (col ^ (((row >> 2) & 7) << 3));
}

__global__ __launch_bounds__(256, 3)
void ntk_attn(const float* __restrict__ Qg, const float* __restrict__ Kg,
              const float* __restrict__ Vg, const float* __restrict__ PKg,
              const float* __restrict__ PKVg, float* __restrict__ Og) {
  __shared__ __bf16 Ks[KVBLK * KSTR];      // K tile [kv][d]
  __shared__ __bf16 Vts[HDIM * VSTR];      // V transposed, swizzled
  __shared__ __bf16 Zts[HDIM * VSTR];      // Z transposed, swizzled
  __shared__ __bf16 Ps[4][2][16 * PSTR];   // per-wave, per-group P tile
  __shared__ float kks[HDIM];
  __shared__ float red[4][2][16];

  const int tid = threadIdx.x;
  const int w = tid >> 6, l = tid & 63, lr = l & 15, lg = l >> 4;
  const int bh = blockIdx.y, h = bh & (NHEAD - 1);
  const int bx = NQT - 1 - blockIdx.x;     // longest blocks dispatch first
  const int q0 = bx * QBLK;
  const int headoff = bh * HDIM;
  const int ntile = 2 * bx + 2;            // KV tiles 0 .. 2bx+1

  // ---- Q fragments (pre-scaled by 1/sqrt(d)) + phi(Q), two row-groups ----
  // Softmax reference fixed at m'=0 (mathematically identical; S ~ N(0,1)).
  bf16x8 aq[2][2], pq[2][2];
#pragma unroll
  for (int g = 0; g < 2; ++g) {
    const float* qp = Qg + (size_t)(q0 + 64 * g + w * 16 + lr) * ROWSTRIDE +
                      headoff + lg * 8;
#pragma unroll
    for (int c = 0; c < 2; ++c) {
      const float4 x0 = *(const float4*)(qp + 32 * c);
      const float4 x1 = *(const float4*)(qp + 32 * c + 4);
      const float f[8] = {x0.x, x0.y, x0.z, x0.w, x1.x, x1.y, x1.z, x1.w};
#pragma unroll
      for (int i = 0; i < 8; ++i) {
        aq[g][c][i] = (__bf16)(f[i] * 0.125f);
        const float xs = f[i] * 0.3535533905932738f;
        pq[g][c][i] = (__bf16)(xs > 0.f ? xs + 1.f : __expf(xs));
      }
    }
  }

  // ---- stage Zt (transposed, swizzled) and |kk| ----
  {
#pragma unroll
    for (int it = 0; it < 4; ++it) {
      const int din = (tid >> 4) + 16 * it;
      const int c4 = (tid & 15) * 4;
      const float4 z = *(const float4*)(PKVg + (size_t)h * HDIM * HDIM +
                                        (size_t)din * HDIM + c4);
      Zts[vswz(c4 + 0, din)] = (__bf16)z.x;
      Zts[vswz(c4 + 1, din)] = (__bf16)z.y;
      Zts[vswz(c4 + 2, din)] = (__bf16)z.z;
      Zts[vswz(c4 + 3, din)] = (__bf16)z.w;
    }
    if (tid < HDIM) kks[tid] = fabsf(PKg[h * HDIM + tid]);
  }

  const f32x4 z4 = {0.f, 0.f, 0.f, 0.f};
  f32x4 oacc[2][4] = {{z4, z4, z4, z4}, {z4, z4, z4, z4}};
  float lsum[2][4] = {{0.f, 0.f, 0.f, 0.f}, {0.f, 0.f, 0.f, 0.f}};
  int qrb[2];
  qrb[0] = q0 + w * 16 + lg * 4;
  qrb[1] = q0 + 64 + w * 16 + lg * 4;

  // ---- register-staged prefetch ----
  const int stg_r = tid >> 4;
  const int stg_c4 = (tid & 15) * 4;
  float4 kreg[4], vreg[4];
  auto issue_k = [&](int kb) {
#pragma unroll
    for (int it = 0; it < 4; ++it)
      kreg[it] = *(const float4*)(Kg + (size_t)(kb * KVBLK + stg_r + 16 * it) * ROWSTRIDE +
                                  headoff + stg_c4);
  };
  auto issue_v = [&](int kb) {
#pragma unroll
    for (int it = 0; it < 4; ++it)
      vreg[it] = *(const float4*)(Vg + (size_t)(kb * KVBLK + stg_r + 16 * it) * ROWSTRIDE +
                                  headoff + stg_c4);
  };
  auto write_k = [&]() {
#pragma unroll
    for (int it = 0; it < 4; ++it) {
      bf16x4 p = {(__bf16)kreg[it].x, (__bf16)kreg[it].y,
                  (__bf16)kreg[it].z, (__bf16)kreg[it].w};
      *(bf16x4*)&Ks[(stg_r + 16 * it) * KSTR + stg_c4] = p;
    }
  };
  auto write_v = [&]() {
#pragma unroll
    for (int it = 0; it < 4; ++it) {
      const int r = stg_r + 16 * it;
      Vts[vswz(stg_c4 + 0, r)] = (__bf16)vreg[it].x;
      Vts[vswz(stg_c4 + 1, r)] = (__bf16)vreg[it].y;
      Vts[vswz(stg_c4 + 2, r)] = (__bf16)vreg[it].z;
      Vts[vswz(stg_c4 + 3, r)] = (__bf16)vreg[it].w;
    }
  };

  // ---- prologue: tile 0 resident, tile 1 in flight ----
  issue_k(0); issue_v(0);
  write_k(); write_v();
  issue_k(1); issue_v(1);   // ntile >= 2 always
  __syncthreads();

  // ==== main loop over causal KV tiles for this 128-row q-block ====
  for (int kb = 0; kb < ntile; ++kb) {
    const int kv0 = kb * KVBLK;
    // group activity: g=0 covers tiles 0..2bx (diag at 2bx);
    //                 g=1 covers tiles 0..2bx+1 (diag at 2bx+1)
    const bool g0act = (kb <= 2 * bx);

    // ---- S = (Q/sqrt(d)) K^T for both row-groups (independent chains) ----
    float sv[2][4][4];
    __builtin_amdgcn_s_setprio(1);
#pragma unroll
    for (int nj = 0; nj < 4; ++nj) {
      f32x4 acc0 = z4, acc1 = z4;
#pragma unroll
      for (int c = 0; c < 2; ++c) {
        const bf16x8 bk = *(const bf16x8*)&Ks[(nj * 16 + lr) * KSTR + 32 * c + lg * 8];
        if (g0act)
          acc0 = __builtin_amdgcn_mfma_f32_16x16x32_bf16(aq[0][c], bk, acc0, 0, 0, 0);
        acc1 = __builtin_amdgcn_mfma_f32_16x16x32_bf16(aq[1][c], bk, acc1, 0, 0, 0);
      }
#pragma unroll
      for (int r = 0; r < 4; ++r) { sv[0][nj][r] = acc0[r]; sv[1][nj][r] = acc1[r]; }
    }
    __builtin_amdgcn_s_setprio(0);

    // ---- P = exp(S) (mask only each group's diagonal tile) -> LDS ----
#pragma unroll
    for (int g = 0; g < 2; ++g) {
      if (g == 0 && !g0act) continue;
      if (kb == 2 * bx + g) {
#pragma unroll
        for (int nj = 0; nj < 4; ++nj) {
          const int col = kv0 + nj * 16 + lr;
#pragma unroll
          for (int r = 0; r < 4; ++r) {
            const float p = (col <= qrb[g] + r) ? __expf(sv[g][nj][r]) : 0.f;
            lsum[g][r] += p;
            Ps[w][g][(lg * 4 + r) * PSTR + nj * 16 + lr] = (__bf16)p;
          }
        }
      } else {
#pragma unroll
        for (int nj = 0; nj < 4; ++nj)
#pragma unroll
          for (int r = 0; r < 4; ++r) {
            const float p = __expf(sv[g][nj][r]);
            lsum[g][r] += p;
            Ps[w][g][(lg * 4 + r) * PSTR + nj * 16 + lr] = (__bf16)p;
          }
      }
    }
    asm volatile("s_waitcnt lgkmcnt(0)" ::: "memory");
    __builtin_amdgcn_sched_barrier(0);

    // ---- O += P V for both groups ----
    __builtin_amdgcn_s_setprio(1);
#pragma unroll
    for (int c = 0; c < 2; ++c) {
      const bf16x8 bv0 = *(const bf16x8*)&Vts[vswz(0 * 16 + lr, 32 * c + lg * 8)];
      const bf16x8 bv1 = *(const bf16x8*)&Vts[vswz(1 * 16 + lr, 32 * c + lg * 8)];
      const bf16x8 bv2 = *(const bf16x8*)&Vts[vswz(2 * 16 + lr, 32 * c + lg * 8)];
      const bf16x8 bv3 = *(const bf16x8*)&Vts[vswz(3 * 16 + lr, 32 * c + lg * 8)];
#pragma unroll
      for (int g = 0; g < 2; ++g) {
        if (g == 0 && !g0act) continue;
        const bf16x8 ap = *(const bf16x8*)&Ps[w][g][lr * PSTR + 32 * c + lg * 8];
        oacc[g][0] = __builtin_amdgcn_mfma_f32_16x16x32_bf16(ap, bv0, oacc[g][0], 0, 0, 0);
        oacc[g][1] = __builtin_amdgcn_mfma_f32_16x16x32_bf16(ap, bv1, oacc[g][1], 0, 0, 0);
        oacc[g][2] = __builtin_amdgcn_mfma_f32_16x16x32_bf16(ap, bv2, oacc[g][2], 0, 0, 0);
        oacc[g][3] = __builtin_amdgcn_mfma_f32_16x16x32_bf16(ap, bv3, oacc[g][3], 0, 0, 0);
      }
    }
    __builtin_amdgcn_s_setprio(0);

    // ---- stage next tile (write kb+1 from regs, issue kb+2) ----
    if (kb < ntile - 1) {
      __syncthreads();
      write_k(); write_v();
      if (kb + 2 < ntile) { issue_k(kb + 2); issue_v(kb + 2); }
      __syncthreads();
    }
  }

  // ---- denominators: rowsum + phi_q.kk per group, broadcast via LDS ----
#pragma unroll
  for (int g = 0; g < 2; ++g) {
    float pkk = 0.f;
#pragma unroll
    for (int c = 0; c < 2; ++c)
#pragma unroll
      for (int i = 0; i < 8; ++i)
        pkk += (float)pq[g][c][i] * kks[32 * c + lg * 8 + i];
    pkk += __shfl_xor(pkk, 16);
    pkk += __shfl_xor(pkk, 32);
    if (l < 16) red[w][g][l] = pkk;
  }
  asm volatile("s_waitcnt lgkmcnt(0)" ::: "memory");
  __builtin_amdgcn_sched_barrier(0);

  // ---- epilogue per group: phi_q @ Z (MFMA), normalize, write ----
#pragma unroll
  for (int g = 0; g < 2; ++g) {
    f32x4 zacc[4] = {z4, z4, z4, z4};
    __builtin_amdgcn_s_setprio(1);
#pragma unroll
    for (int c = 0; c < 2; ++c) {
#pragma unroll
      for (int dj = 0; dj < 4; ++dj) {
        const bf16x8 bz = *(const bf16x8*)&Zts[vswz(dj * 16 + lr, 32 * c + lg * 8)];
        zacc[dj] = __builtin_amdgcn_mfma_f32_16x16x32_bf16(pq[g][c], bz, zacc[dj], 0, 0, 0);
      }
    }
    __builtin_amdgcn_s_setprio(0);
#pragma unroll
    for (int r = 0; r < 4; ++r) {
      float s = lsum[g][r];
      s += __shfl_xor(s, 1); s += __shfl_xor(s, 2);
      s += __shfl_xor(s, 4); s += __shfl_xor(s, 8);
      const float rd = 1.f / (s + red[w][g][lg * 4 + r]);
      float* op = Og + (size_t)(q0 + 64 * g + w * 16 + lg * 4 + r) * ROWSTRIDE + headoff;
#pragma unroll
      for (int dj = 0; dj < 4; ++dj)
        op[dj * 16 + lr] = (oacc[g][dj][r] + zacc[dj][r]) * rd;
    }
  }
}

extern "C" void kernel_launch(void* const* d_in, const int* in_sizes, int n_in,
                              void* d_out, int out_size, void* d_ws, size_t ws_size,
                              hipStream_t stream) {
  const float* Qg  = (const float*)d_in[0];
  const float* Kg  = (const float*)d_in[1];
  const float* Vg  = (const float*)d_in[2];
  const float* PKg  = (const float*)d_in[4];
  const float* PKVg = (const float*)d_in[5];
  float* Og = (float*)d_out;
  dim3 grid(NQT, BSZ * NHEAD);
  ntk_attn<<<grid, dim3(256), 0, stream>>>(Qg, Kg, Vg, PKg, PKVg, Og);
}